// Round 9
// baseline (209.199 us; speedup 1.0000x reference)
//
#include <hip/hip_runtime.h>
#include <hip/hip_bf16.h>

#define N_Q 256
#define M_S 1024
#define DD 512
#define HH 512

typedef __attribute__((ext_vector_type(8))) short short8;
typedef __attribute__((ext_vector_type(8))) __bf16 bf16x8;
typedef __attribute__((ext_vector_type(16))) float f32x16;
typedef __attribute__((ext_vector_type(2))) __bf16 bf16x2;

union U8 { short8 s; bf16x8 b; };

__device__ __forceinline__ unsigned short f2bf(float f) {
  unsigned int u = __float_as_uint(f);
  u += 0x7FFFu + ((u >> 16) & 1u);
  return (unsigned short)(u >> 16);
}

__device__ __forceinline__ short8 pack8(const float* d) {
#if defined(__has_builtin) && __has_builtin(__builtin_amdgcn_cvt_pk_bf16_f32)
  short8 r;
#pragma unroll
  for (int i = 0; i < 4; ++i) {
    union { bf16x2 v; short s[2]; } u;
    u.v = __builtin_amdgcn_cvt_pk_bf16_f32(d[2 * i], d[2 * i + 1]);
    r[2 * i] = u.s[0];
    r[2 * i + 1] = u.s[1];
  }
  return r;
#else
  short8 r;
#pragma unroll
  for (int i = 0; i < 8; ++i) r[i] = (short)f2bf(d[i]);
  return r;
#endif
}

__device__ __forceinline__ short8 packdiff(float4 e0, float4 e1, float4 s0, float4 s1) {
  float d[8];
  d[0] = fabsf(e0.x - s0.x); d[1] = fabsf(e0.y - s0.y);
  d[2] = fabsf(e0.z - s0.z); d[3] = fabsf(e0.w - s0.w);
  d[4] = fabsf(e1.x - s1.x); d[5] = fabsf(e1.y - s1.y);
  d[6] = fabsf(e1.z - s1.z); d[7] = fabsf(e1.w - s1.w);
  return pack8(d);
}

// W1 [D][H] fp32 -> w1s in MFMA-fragment order.
// Fragment map (verified): w1s[f*512 + l*8 + j] = W1[k][h] with
//   f = (k>>4)*16 + (h>>5), l = ((k>>3)&1)*32 + (h&31), j = k&7.
__global__ __launch_bounds__(1024) void prep_w1s(const float* __restrict__ W1,
                                                 unsigned short* __restrict__ w1s) {
  const int gid = blockIdx.x * 1024 + threadIdx.x;  // 0..65535
  const int k = gid >> 7;                            // 0..511
  const int hq = gid & 127;                          // h-quad
  const float4 w = *(const float4*)(W1 + k * HH + hq * 4);
  const int f = (k >> 4) * 16 + (hq >> 3);
  const int lk = ((k >> 3) & 1) * 32 + (hq & 7) * 4; // l base for i=0
  const int j = k & 7;
  unsigned short* p = w1s + f * 512 + lk * 8 + j;    // stride 8 shorts per h
  p[0]  = f2bf(w.x);
  p[8]  = f2bf(w.y);
  p[16] = f2bf(w.z);
  p[24] = f2bf(w.w);
}

// Block: 512 thr = 8 waves. Tile 128 pairs x 512 h x K=512. A (diff) resident
// in 128 KB LDS ([p][c ^ (p&15)], 0 bank conflicts). W1 streams through a
// 2x16 KB LDS double-buffer, self-staged per wave via global_load_lds.
// R9 change: BARRIER-LOCKED m201-STYLE PHASES (T3+T4). Per ks-phase:
//   w-reads(ks) from wbuf[ks&1] -> lgkmcnt(0) -> s_barrier (buffer free)
//   -> STAGE(ks+2) into wbuf[ks&1] -> setprio/8 MFMA/setprio
//   -> a-ring reads(ks+1) (A-tile never clobbered -> ring-2 post-cluster)
//   -> vmcnt(2) (counted: stage(ks+1) landed, stage(ks+2) in flight)
//   -> s_barrier.
// Theory: R1-R8's free-running loops all sat at ~1300 cyc/ks (MfmaUtil
// 40-46%) regardless of conflicts/ordering/FIFO; m201/m233 show the
// barrier-locked counted-vmcnt schedule reaches 62% MfmaUtil at this same
// 2-waves/SIMD occupancy while MFMA-only hits 86% -> structure, not
// occupancy, is the lever. Race safety: stage(p)->wbuf[p&1] is issued only
// after the mid-phase barrier proves ALL waves' reads of wbuf[p&1] complete
// (lgkmcnt(0) precedes it in every wave).
__global__ __launch_bounds__(512, 2) void support_kernel(
    const float* __restrict__ emb, const float* __restrict__ sup,
    const unsigned short* __restrict__ w1s, const float* __restrict__ b1,
    const float* __restrict__ W2, const float* __restrict__ b2,
    float* __restrict__ out) {
  extern __shared__ char lds[];
  short8* As16 = (short8*)lds;             // [128][64] chunks, 131072 B
  char* wbuf = lds + 131072;               // [2][8 waves][2048 B] = 32768 B

  const int tid = threadIdx.x;
  const int lane = tid & 63;
  const int wid = tid >> 6;          // 0..7 = hslice (h base = wid*64)
  const int l31 = lane & 31;
  const int khalf = lane >> 5;

  const int m0 = blockIdx.x * 16;
  const int n0 = blockIdx.y * 8;

  // per-lane global source base for this wave's W1 frag slice
  const char* gW = (const char*)w1s + (wid * 2) * 1024 + lane * 16;
  const int wslice = wid * 2048;     // wave-uniform LDS slice offset

#define STAGE_W1(KS) do {                                                     \
    const char* _g = gW + (KS) * 16384;                                       \
    char* _l = wbuf + (((KS) & 1) * 16384 + wslice);                          \
    __builtin_amdgcn_global_load_lds(                                         \
        (const __attribute__((address_space(1))) unsigned int*)(_g),          \
        (__attribute__((address_space(3))) unsigned int*)(_l), 16, 0, 0);     \
    __builtin_amdgcn_global_load_lds(                                         \
        (const __attribute__((address_space(1))) unsigned int*)(_g + 1024),   \
        (__attribute__((address_space(3))) unsigned int*)(_l + 1024), 16, 0, 0); \
  } while (0)

  // ---- stage 128p x 512k diffs (once): thread = (emb row rg, k-chunk c) ----
  {
    const int c = tid & 63;
    const int rg = tid >> 6;           // emb row 0..7
    const float* ep = emb + (n0 + rg) * DD + c * 8;
    const float4 e0 = *(const float4*)ep;
    const float4 e1 = *(const float4*)(ep + 4);
    const float* sbase = sup + m0 * DD + c * 8;
#pragma unroll
    for (int j = 0; j < 16; ++j) {     // 16 sup rows; p = rg*16+j, p&15 == j
      const float4 s0 = *(const float4*)(sbase + j * DD);
      const float4 s1 = *(const float4*)(sbase + j * DD + 4);
      As16[(rg * 16 + j) * 64 + (c ^ j)] = packdiff(e0, e1, s0, s1);
    }
  }
  // W1 dbuf prologue: stage ks=0,1
  STAGE_W1(0);
  STAGE_W1(1);
  __syncthreads();  // barrier A: A-tile visible; vmcnt/lgkm drained

  // ---- K-loop: 32 barrier-locked phases of 16 k, 8 MFMA each ----
  const int ax = l31 & 15;           // read-side chunk XOR (row&15 == l31&15)
  const int ar0 = (0 * 32 + l31) * 64;
  const int ar1 = (1 * 32 + l31) * 64;
  const int ar2 = (2 * 32 + l31) * 64;
  const int ar3 = (3 * 32 + l31) * 64;

  f32x16 acc[4][2] = {};
  U8 a[2][4];
  {  // a-ring prologue: phase 0 operands
    const int c0 = (0 * 2 + khalf) ^ ax;
    a[0][0].s = As16[ar0 + c0];
    a[0][1].s = As16[ar1 + c0];
    a[0][2].s = As16[ar2 + c0];
    a[0][3].s = As16[ar3 + c0];
  }
  U8 w[2];

#pragma unroll
  for (int ks = 0; ks < 32; ++ks) {
    // w-frag reads for THIS phase from wbuf[ks&1]
    {
      const short8* wp = (const short8*)(wbuf + ((ks & 1) * 16384 + wslice));
      w[0].s = wp[lane];
      w[1].s = wp[64 + lane];
    }
    asm volatile("s_waitcnt lgkmcnt(0)" ::: "memory");  // reads done; wbuf free
    __builtin_amdgcn_sched_barrier(0);                  // rule #18 fence
    __builtin_amdgcn_s_barrier();   // ALL waves done reading wbuf[ks&1]
    if (ks + 2 < 32) STAGE_W1(ks + 2);  // overwrite wbuf[ks&1] (now safe)
    __builtin_amdgcn_s_setprio(1);
#pragma unroll
    for (int am = 0; am < 4; ++am)
#pragma unroll
      for (int tj = 0; tj < 2; ++tj)
        acc[am][tj] = __builtin_amdgcn_mfma_f32_32x32x16_bf16(
            w[tj].b, a[ks & 1][am].b, acc[am][tj], 0, 0, 0);
    __builtin_amdgcn_s_setprio(0);
    if (ks + 1 < 32) {  // a-ring reads for next phase (A-tile clobber-free)
      const int cc = ((ks + 1) * 2 + khalf) ^ ax;
      a[(ks + 1) & 1][0].s = As16[ar0 + cc];
      a[(ks + 1) & 1][1].s = As16[ar1 + cc];
      a[(ks + 1) & 1][2].s = As16[ar2 + cc];
      a[(ks + 1) & 1][3].s = As16[ar3 + cc];
    }
    if (ks + 2 < 32) {
      asm volatile("s_waitcnt vmcnt(2)" ::: "memory");  // stage(ks+1) landed
      __builtin_amdgcn_s_barrier();  // wbuf[(ks+1)&1] globally ready
    } else if (ks == 30) {
      asm volatile("s_waitcnt vmcnt(0)" ::: "memory");  // stage(31) landed
      __builtin_amdgcn_s_barrier();
    }
    // ks == 31: no trailing barrier needed
  }
#undef STAGE_W1

  // ---- epilogue: C col = pair (l31 + am*32), row = h: (r&3)+8*(r>>2)+4*khalf
  // In-lane reduce over 64 h per wave; one xor-32 shuffle per am.
  float s0a, s1a, s2a, s3a;
  {
    float sm[4] = {0.f, 0.f, 0.f, 0.f};
#pragma unroll
    for (int tj = 0; tj < 2; ++tj) {
      const float* b1p = b1 + (wid * 2 + tj) * 32 + khalf * 4;
      const float* w2p = W2 + (wid * 2 + tj) * 32 + khalf * 4;
#pragma unroll
      for (int rq = 0; rq < 4; ++rq) {
        const float4 b1q = *(const float4*)(b1p + rq * 8);
        const float4 w2q = *(const float4*)(w2p + rq * 8);
#pragma unroll
        for (int am = 0; am < 4; ++am) {
          sm[am] += fmaxf(acc[am][tj][rq * 4 + 0] + b1q.x, 0.f) * w2q.x;
          sm[am] += fmaxf(acc[am][tj][rq * 4 + 1] + b1q.y, 0.f) * w2q.y;
          sm[am] += fmaxf(acc[am][tj][rq * 4 + 2] + b1q.z, 0.f) * w2q.z;
          sm[am] += fmaxf(acc[am][tj][rq * 4 + 3] + b1q.w, 0.f) * w2q.w;
        }
      }
    }
#pragma unroll
    for (int am = 0; am < 4; ++am) sm[am] += __shfl_xor(sm[am], 32, 64);
    s0a = sm[0]; s1a = sm[1]; s2a = sm[2]; s3a = sm[3];
  }
  __syncthreads();  // all As16 reads done; safe to alias psums
  float* psums = (float*)As16;  // [128 pairs][9] (pad 9 -> conflict-free)
  {
    const float v0 = khalf ? s2a : s0a;
    const float v1 = khalf ? s3a : s1a;
    const int p0 = khalf * 64 + l31;       // am = khalf*2     -> pair base
    psums[p0 * 9 + wid] = v0;
    psums[(p0 + 32) * 9 + wid] = v1;       // am = khalf*2 + 1
  }
  __syncthreads();  // psums visible
  if (tid < 128) {
    float t = b2[0];
#pragma unroll
    for (int w8 = 0; w8 < 8; ++w8) t += psums[tid * 9 + w8];
    out[(n0 + (tid >> 4)) * M_S + m0 + (tid & 15)] = 1.f / (1.f + __expf(-t));
  }
}

extern "C" void kernel_launch(void* const* d_in, const int* in_sizes, int n_in,
                              void* d_out, int out_size, void* d_ws, size_t ws_size,
                              hipStream_t stream) {
  const float* emb = (const float*)d_in[0];
  const float* sup = (const float*)d_in[1];
  const float* W1  = (const float*)d_in[2];
  const float* b1  = (const float*)d_in[3];
  const float* W2  = (const float*)d_in[4];
  const float* b2  = (const float*)d_in[5];
  float* out = (float*)d_out;
  unsigned short* w1s = (unsigned short*)d_ws;  // 512 KB fragment-ordered W1

  static bool attr_done = false;
  if (!attr_done) {
    hipFuncSetAttribute((const void*)support_kernel,
                        hipFuncAttributeMaxDynamicSharedMemorySize, 163840);
    attr_done = true;
  }

  prep_w1s<<<64, 1024, 0, stream>>>(W1, w1s);
  support_kernel<<<dim3(M_S / 16, N_Q / 8), 512, 163840, stream>>>(
      emb, sup, w1s, b1, W2, b2, out);
}

// Round 10
// 190.253 us; speedup vs baseline: 1.0996x; 1.0996x over previous
//
#include <hip/hip_runtime.h>
#include <hip/hip_bf16.h>

#define N_Q 256
#define M_S 1024
#define DD 512
#define HH 512

typedef __attribute__((ext_vector_type(8))) short short8;
typedef __attribute__((ext_vector_type(8))) __bf16 bf16x8;
typedef __attribute__((ext_vector_type(16))) float f32x16;
typedef __attribute__((ext_vector_type(2))) __bf16 bf16x2;
typedef __attribute__((ext_vector_type(4))) int i32x4;

union U8 { short8 s; bf16x8 b; i32x4 i; };

__device__ __forceinline__ unsigned short f2bf(float f) {
  unsigned int u = __float_as_uint(f);
  u += 0x7FFFu + ((u >> 16) & 1u);
  return (unsigned short)(u >> 16);
}

__device__ __forceinline__ short8 pack8(const float* d) {
#if defined(__has_builtin) && __has_builtin(__builtin_amdgcn_cvt_pk_bf16_f32)
  short8 r;
#pragma unroll
  for (int i = 0; i < 4; ++i) {
    union { bf16x2 v; short s[2]; } u;
    u.v = __builtin_amdgcn_cvt_pk_bf16_f32(d[2 * i], d[2 * i + 1]);
    r[2 * i] = u.s[0];
    r[2 * i + 1] = u.s[1];
  }
  return r;
#else
  short8 r;
#pragma unroll
  for (int i = 0; i < 8; ++i) r[i] = (short)f2bf(d[i]);
  return r;
#endif
}

__device__ __forceinline__ short8 packdiff(float4 e0, float4 e1, float4 s0, float4 s1) {
  float d[8];
  d[0] = fabsf(e0.x - s0.x); d[1] = fabsf(e0.y - s0.y);
  d[2] = fabsf(e0.z - s0.z); d[3] = fabsf(e0.w - s0.w);
  d[4] = fabsf(e1.x - s1.x); d[5] = fabsf(e1.y - s1.y);
  d[6] = fabsf(e1.z - s1.z); d[7] = fabsf(e1.w - s1.w);
  return pack8(d);
}

// W1 [D][H] fp32 -> w1s in MFMA-fragment order.
// Fragment map (verified): w1s[f*512 + l*8 + j] = W1[k][h] with
//   f = (k>>4)*16 + (h>>5), l = ((k>>3)&1)*32 + (h&31), j = k&7.
__global__ __launch_bounds__(1024) void prep_w1s(const float* __restrict__ W1,
                                                 unsigned short* __restrict__ w1s) {
  const int gid = blockIdx.x * 1024 + threadIdx.x;  // 0..65535
  const int k = gid >> 7;                            // 0..511
  const int hq = gid & 127;                          // h-quad
  const float4 w = *(const float4*)(W1 + k * HH + hq * 4);
  const int f = (k >> 4) * 16 + (hq >> 3);
  const int lk = ((k >> 3) & 1) * 32 + (hq & 7) * 4; // l base for i=0
  const int j = k & 7;
  unsigned short* p = w1s + f * 512 + lk * 8 + j;    // stride 8 shorts per h
  p[0]  = f2bf(w.x);
  p[8]  = f2bf(w.y);
  p[16] = f2bf(w.z);
  p[24] = f2bf(w.w);
}

// Block: 512 thr = 8 waves. Tile 128 pairs x 512 h x K=512. A (diff) resident
// in 128 KB LDS ([p][c ^ (p&15)], 0 bank conflicts). Wave wid = hslice (64 h),
// acc[4][2] (128 AGPR). MFMA operand-swapped; C col = pair, row = h.
// R10 change: ASM-PINNED K-LOOP PIPELINE. Theory: rocprof VGPR_Count ~100
// across R3-R9 proves the compiler never kept the source-level prefetch
// rings register-resident (a-ring alone needs ~48 VGPR on top of 128 AGPR +
// b-ring 32) — LLVM sank the loads toward uses, collapsing prefetch distance
// to ~0 and exposing ds/L2 latency every phase (~800 cyc/ks stall, invariant
// across all 6 source-level restructurings). Fix at ISA level (HK T3/T4):
//   - a-frags: asm volatile ds_read_b128, depth-2 ring, issued post-cluster
//   - W1-frags: asm volatile global_load_dwordx4 (SGPR base + voffset)
//   - per phase: s_waitcnt lgkmcnt(4) / vmcnt(2) counted (drain 0 only at
//     ks=31), each + sched_barrier(0) (rule #18)
// asm volatile ops are mutually ordered; outputs are forced live ~2 phases.
__global__ __launch_bounds__(512, 2) void support_kernel(
    const float* __restrict__ emb, const float* __restrict__ sup,
    const unsigned short* __restrict__ w1s, const float* __restrict__ b1,
    const float* __restrict__ W2, const float* __restrict__ b2,
    float* __restrict__ out) {
  extern __shared__ char lds[];
  short8* As16 = (short8*)lds;             // [128][64] chunks, 131072 B
  float* psums = (float*)(lds + 131072);   // [128][9], 4608 B

  const int tid = threadIdx.x;
  const int lane = tid & 63;
  const int wid = tid >> 6;          // 0..7 = hslice (h base = wid*64)
  const int l31 = lane & 31;
  const int khalf = lane >> 5;

  const int m0 = blockIdx.x * 16;
  const int n0 = blockIdx.y * 8;

  // ---- stage 128p x 512k diffs (once): thread = (emb row rg, k-chunk c) ----
  {
    const int c = tid & 63;
    const int rg = tid >> 6;           // emb row 0..7
    const float* ep = emb + (n0 + rg) * DD + c * 8;
    const float4 e0 = *(const float4*)ep;
    const float4 e1 = *(const float4*)(ep + 4);
    const float* sbase = sup + m0 * DD + c * 8;
#pragma unroll
    for (int j = 0; j < 16; ++j) {     // 16 sup rows; p = rg*16+j, p&15 == j
      const float4 s0 = *(const float4*)(sbase + j * DD);
      const float4 s1 = *(const float4*)(sbase + j * DD + 4);
      As16[(rg * 16 + j) * 64 + (c ^ j)] = packdiff(e0, e1, s0, s1);
    }
  }
  __syncthreads();  // barrier A: A-tile visible; all counters drained

  // ---- K-loop: 32 phases of 16 k, 8 MFMA each; asm-pinned pipeline ----
  const int ax = l31 & 15;           // read-side chunk XOR (row&15 == l31&15)
  const unsigned aB0 = (unsigned)(uintptr_t)(As16 + (0 * 32 + l31) * 64);
  const unsigned aB1 = (unsigned)(uintptr_t)(As16 + (1 * 32 + l31) * 64);
  const unsigned aB2 = (unsigned)(uintptr_t)(As16 + (2 * 32 + l31) * 64);
  const unsigned aB3 = (unsigned)(uintptr_t)(As16 + (3 * 32 + l31) * 64);
  // W1 voffset base (bytes): wave slice + lane. ks adds ks*16384, tj adds 1024.
  const unsigned vbase = (unsigned)(wid * 2048 + lane * 16);

  f32x16 acc[4][2] = {};
  U8 a[2][4], b[2][2];

#define A_ISSUE(SLOT, PH) do {                                                \
    const unsigned _x = (((unsigned)(2 * (PH) + khalf)) ^ (unsigned)ax) << 4; \
    asm volatile("ds_read_b128 %0, %1" : "=v"(a[SLOT][0].i) : "v"(aB0 + _x)); \
    asm volatile("ds_read_b128 %0, %1" : "=v"(a[SLOT][1].i) : "v"(aB1 + _x)); \
    asm volatile("ds_read_b128 %0, %1" : "=v"(a[SLOT][2].i) : "v"(aB2 + _x)); \
    asm volatile("ds_read_b128 %0, %1" : "=v"(a[SLOT][3].i) : "v"(aB3 + _x)); \
  } while (0)
#define B_ISSUE(SLOT, PH) do {                                                \
    const unsigned _vo = vbase + (unsigned)(PH) * 16384u;                     \
    asm volatile("global_load_dwordx4 %0, %1, %2"                             \
                 : "=v"(b[SLOT][0].i) : "v"(_vo), "s"(w1s) : "memory");       \
    asm volatile("global_load_dwordx4 %0, %1, %2 offset:1024"                 \
                 : "=v"(b[SLOT][1].i) : "v"(_vo), "s"(w1s) : "memory");       \
  } while (0)

  // prologue: a(0),a(1) then b(0),b(1)
  A_ISSUE(0, 0);
  A_ISSUE(1, 1);
  B_ISSUE(0, 0);
  B_ISSUE(1, 1);

#pragma unroll
  for (int ks = 0; ks < 32; ++ks) {
    if (ks < 31) {
      asm volatile("s_waitcnt lgkmcnt(4)" ::: "memory");  // a(ks) landed
      __builtin_amdgcn_sched_barrier(0);
      asm volatile("s_waitcnt vmcnt(2)" ::: "memory");    // b(ks) landed
      __builtin_amdgcn_sched_barrier(0);
    } else {
      asm volatile("s_waitcnt lgkmcnt(0)" ::: "memory");
      __builtin_amdgcn_sched_barrier(0);
      asm volatile("s_waitcnt vmcnt(0)" ::: "memory");
      __builtin_amdgcn_sched_barrier(0);
    }
    __builtin_amdgcn_s_setprio(1);
#pragma unroll
    for (int am = 0; am < 4; ++am)
#pragma unroll
      for (int tj = 0; tj < 2; ++tj)
        acc[am][tj] = __builtin_amdgcn_mfma_f32_32x32x16_bf16(
            b[ks & 1][tj].b, a[ks & 1][am].b, acc[am][tj], 0, 0, 0);
    __builtin_amdgcn_s_setprio(0);
    if (ks + 2 < 32) {  // refill just-consumed slot with phase ks+2 data
      A_ISSUE(ks & 1, ks + 2);
      B_ISSUE(ks & 1, ks + 2);
    }
  }
#undef A_ISSUE
#undef B_ISSUE

  // ---- epilogue: C col = pair (l31 + am*32), row = h: (r&3)+8*(r>>2)+4*khalf
  // In-lane reduce over 64 h per wave; one xor-32 shuffle per am.
  float s0a, s1a, s2a, s3a;
  {
    float sm[4] = {0.f, 0.f, 0.f, 0.f};
#pragma unroll
    for (int tj = 0; tj < 2; ++tj) {
      const float* b1p = b1 + (wid * 2 + tj) * 32 + khalf * 4;
      const float* w2p = W2 + (wid * 2 + tj) * 32 + khalf * 4;
#pragma unroll
      for (int rq = 0; rq < 4; ++rq) {
        const float4 b1q = *(const float4*)(b1p + rq * 8);
        const float4 w2q = *(const float4*)(w2p + rq * 8);
#pragma unroll
        for (int am = 0; am < 4; ++am) {
          sm[am] += fmaxf(acc[am][tj][rq * 4 + 0] + b1q.x, 0.f) * w2q.x;
          sm[am] += fmaxf(acc[am][tj][rq * 4 + 1] + b1q.y, 0.f) * w2q.y;
          sm[am] += fmaxf(acc[am][tj][rq * 4 + 2] + b1q.z, 0.f) * w2q.z;
          sm[am] += fmaxf(acc[am][tj][rq * 4 + 3] + b1q.w, 0.f) * w2q.w;
        }
      }
    }
#pragma unroll
    for (int am = 0; am < 4; ++am) sm[am] += __shfl_xor(sm[am], 32, 64);
    s0a = sm[0]; s1a = sm[1]; s2a = sm[2]; s3a = sm[3];
  }
  // psums in dedicated region beyond the A tile — no aliasing barrier needed
  {
    const float v0 = khalf ? s2a : s0a;
    const float v1 = khalf ? s3a : s1a;
    const int p0 = khalf * 64 + l31;       // am = khalf*2     -> pair base
    psums[p0 * 9 + wid] = v0;
    psums[(p0 + 32) * 9 + wid] = v1;       // am = khalf*2 + 1
  }
  __syncthreads();  // psums visible
  if (tid < 128) {
    float t = b2[0];
#pragma unroll
    for (int w8 = 0; w8 < 8; ++w8) t += psums[tid * 9 + w8];
    out[(n0 + (tid >> 4)) * M_S + m0 + (tid & 15)] = 1.f / (1.f + __expf(-t));
  }
}

extern "C" void kernel_launch(void* const* d_in, const int* in_sizes, int n_in,
                              void* d_out, int out_size, void* d_ws, size_t ws_size,
                              hipStream_t stream) {
  const float* emb = (const float*)d_in[0];
  const float* sup = (const float*)d_in[1];
  const float* W1  = (const float*)d_in[2];
  const float* b1  = (const float*)d_in[3];
  const float* W2  = (const float*)d_in[4];
  const float* b2  = (const float*)d_in[5];
  float* out = (float*)d_out;
  unsigned short* w1s = (unsigned short*)d_ws;  // 512 KB fragment-ordered W1

  static bool attr_done = false;
  if (!attr_done) {
    hipFuncSetAttribute((const void*)support_kernel,
                        hipFuncAttributeMaxDynamicSharedMemorySize, 135680);
    attr_done = true;
  }

  prep_w1s<<<64, 1024, 0, stream>>>(W1, w1s);
  support_kernel<<<dim3(M_S / 16, N_Q / 8), 512, 135680, stream>>>(
      emb, sup, w1s, b1, W2, b2, out);
}